// Round 7
// baseline (118.110 us; speedup 1.0000x reference)
//
#include <hip/hip_runtime.h>
#include <math.h>

// MultiHeadGAT fused pipeline, round 7.
// k1: 256x256, BK=64, 8 waves INTERLEAVED tiling (rows (2mi+wm)*16, cols
//     (4ni+wn)*16), 4-phase counted-vmcnt schedule (one barrier + 16 MFMA
//     per phase, vmcnt(4) never 0 in main loop), R4's proven (r&7)<<4
//     both-sides swizzle, setprio around MFMA. Tail unchanged.

#define NH   4
#define TD   768
#define HID  256
#define OD   768
#define BB   16
#define LL   1024
#define RTOT (BB*LL)   // 16384 rows per head

typedef __attribute__((ext_vector_type(8))) short bf16x8;
typedef __attribute__((ext_vector_type(4))) float f32x4;

__device__ __forceinline__ float lrelu(float x) { return fmaxf(x, 0.01f * x); }

__device__ __forceinline__ float waveReduceSum(float v) {
  #pragma unroll
  for (int m = 1; m < 64; m <<= 1) v += __shfl_xor(v, m, 64);
  return v;
}
__device__ __forceinline__ float waveReduceMax(float v) {
  #pragma unroll
  for (int m = 1; m < 64; m <<= 1) v = fmaxf(v, __shfl_xor(v, m, 64));
  return v;
}
__device__ __forceinline__ float red16(float v) {   // reduce across 16-lane group
  v += __shfl_xor(v, 1, 64); v += __shfl_xor(v, 2, 64);
  v += __shfl_xor(v, 4, 64); v += __shfl_xor(v, 8, 64);
  return v;
}

__device__ __forceinline__ unsigned short f2b(float f) {  // f32 -> bf16 RNE
  union { float f; unsigned u; } v; v.f = f;
  unsigned u = v.u;
  return (unsigned short)((u + 0x7fffu + ((u >> 16) & 1u)) >> 16);
}
__device__ __forceinline__ float b2f(unsigned short h) {
  union { unsigned u; float f; } v; v.u = ((unsigned)h) << 16;
  return v.f;
}

__device__ __forceinline__ void gll16(const void* g, void* l) {
  __builtin_amdgcn_global_load_lds(
      (const __attribute__((address_space(1))) unsigned int*)g,
      (__attribute__((address_space(3))) unsigned int*)l, 16, 0, 0);
}

// ---- fused conversion kernel ----------------------------------------------
// blocks [0,6144): T fp32 -> bf16.  blocks [6144,6336): Wfc -> Wt bf16 (transp)
__global__ __launch_bounds__(256) void kconv(const float* __restrict__ T,
                                             const float* __restrict__ Wfc,
                                             unsigned short* __restrict__ Tb,
                                             unsigned short* __restrict__ Wtb) {
  __shared__ float tile[64][65];
  const int t = threadIdx.x;
  if (blockIdx.x < 6144) {
    const size_t i = ((size_t)blockIdx.x * 256 + t) * 8;
    const float4 a = *(const float4*)(T + i);
    const float4 b = *(const float4*)(T + i + 4);
    bf16x8 o;
    o[0] = (short)f2b(a.x); o[1] = (short)f2b(a.y);
    o[2] = (short)f2b(a.z); o[3] = (short)f2b(a.w);
    o[4] = (short)f2b(b.x); o[5] = (short)f2b(b.y);
    o[6] = (short)f2b(b.z); o[7] = (short)f2b(b.w);
    *(bf16x8*)(Tb + i) = o;
  } else {
    const int b2 = blockIdx.x - 6144;       // [0,192)
    const int ct = b2 & 3;
    const int kt = (b2 >> 2) % 12;
    const int n  = b2 / 48;
    #pragma unroll
    for (int i = 0; i < 16; ++i) {
      const int kl = i * 4 + (t >> 6), cl = t & 63;
      tile[kl][cl] =
          Wfc[(size_t)n * TD * HID + (size_t)(kt * 64 + kl) * HID + ct * 64 + cl];
    }
    __syncthreads();
    #pragma unroll
    for (int i = 0; i < 16; ++i) {
      const int cl = i * 4 + (t >> 6), kl = t & 63;
      Wtb[(size_t)n * HID * TD + (size_t)(ct * 64 + cl) * TD + kt * 64 + kl] =
          f2b(tile[kl][cl]);
    }
  }
}

// ---- K1: 256x256 MFMA GEMM, 4-phase counted-vmcnt schedule -----------------
// grid = 4 heads x 64 m-blocks; 8 waves: wm=wq>>2, wn=wq&3 (interleaved tiling:
// acc[mi][ni] covers row (2mi+wm)*16, col (4ni+wn)*16).
// LDS: 2 slots x { A[256][64k] 32KB | B[256][64k] 32KB } = 128KB.
// Pieces per K-tile: Ah0 (rows 0-127), Bh0, Bh1, Ah1 — issued 1/phase,
// consumed in issue order one K-tile later. Swizzle byte ^= (r&7)<<4.
__global__ __launch_bounds__(512, 2) void k1_mfma(
    const unsigned short* __restrict__ Tb,   // [16384][768] bf16
    const unsigned short* __restrict__ Wtb,  // [4][256][768] bf16 (W^T)
    const float* __restrict__ bfc, const float* __restrict__ lng,
    const float* __restrict__ lnb, const float* __restrict__ aw,
    unsigned short* __restrict__ hb,         // [4][16384][256] bf16
    float* __restrict__ sR, float* __restrict__ sC)
{
  const int n    = blockIdx.x >> 6;
  const int mb   = blockIdx.x & 63;
  const int t    = threadIdx.x;
  const int lane = t & 63;
  const int wq   = __builtin_amdgcn_readfirstlane(t >> 6);
  const int wm   = wq >> 2;          // 0..1
  const int wn   = wq & 3;           // 0..3
  const int cl   = lane & 15;
  const int rg   = lane >> 4;
  const int row0 = mb * 256;

  __shared__ __align__(16) char smem[131072];

  f32x4 acc[8][4];
  #pragma unroll
  for (int mi = 0; mi < 8; ++mi)
    #pragma unroll
    for (int ni = 0; ni < 4; ++ni) acc[mi][ni] = (f32x4){0.f, 0.f, 0.f, 0.f};

  const char* Tg = (const char*)Tb;
  const char* Wg = (const char*)(Wtb + (size_t)n * HID * TD);

  // issue one 16KB piece (2 x 8KB gll rounds). half in {0,1}.
  #define ISSUE_A(Ns, k0, half)                                                \
    do {                                                                       \
      _Pragma("unroll")                                                        \
      for (int j_ = 0; j_ < 2; ++j_) {                                         \
        const int r_  = (half) * 128 + j_ * 64 + (t >> 3);                     \
        const int kb_ = (t & 7) * 16;                                          \
        gll16(Tg + ((size_t)(row0 + r_) * TD + (k0)) * 2 +                     \
                  (kb_ ^ ((r_ & 7) << 4)),                                     \
              (Ns) + (half) * 16384 + j_ * 8192 + t * 16);                     \
      }                                                                        \
    } while (0)
  #define ISSUE_B(Ns, k0, half)                                                \
    do {                                                                       \
      _Pragma("unroll")                                                        \
      for (int j_ = 0; j_ < 2; ++j_) {                                         \
        const int c_  = (half) * 128 + j_ * 64 + (t >> 3);                     \
        const int kb_ = (t & 7) * 16;                                          \
        gll16(Wg + ((size_t)c_ * TD + (k0)) * 2 + (kb_ ^ ((c_ & 7) << 4)),     \
              (Ns) + 32768 + (half) * 16384 + j_ * 8192 + t * 16);             \
      }                                                                        \
    } while (0)

  #define DSR(MH, NH)                                                          \
    _Pragma("unroll")                                                          \
    for (int m2 = 0; m2 < 4; ++m2) {                                           \
      const int r_ = (2 * ((MH) * 4 + m2) + wm) * 16 + cl;                     \
      _Pragma("unroll")                                                        \
      for (int ks = 0; ks < 2; ++ks)                                           \
        av[m2][ks] = *(const bf16x8*)(As + r_ * 128 +                          \
                         ((ks * 64 + rg * 16) ^ ((r_ & 7) << 4)));             \
    }                                                                          \
    _Pragma("unroll")                                                          \
    for (int n2 = 0; n2 < 2; ++n2) {                                           \
      const int c_ = (4 * ((NH) * 2 + n2) + wn) * 16 + cl;                     \
      _Pragma("unroll")                                                        \
      for (int ks = 0; ks < 2; ++ks)                                           \
        bv[n2][ks] = *(const bf16x8*)(Bs + c_ * 128 +                          \
                         ((ks * 64 + rg * 16) ^ ((c_ & 7) << 4)));             \
    }

  #define MFM(MH, NH)                                                          \
    __builtin_amdgcn_s_setprio(1);                                             \
    _Pragma("unroll")                                                          \
    for (int m2 = 0; m2 < 4; ++m2)                                             \
      _Pragma("unroll")                                                        \
      for (int n2 = 0; n2 < 2; ++n2)                                           \
        _Pragma("unroll")                                                      \
        for (int ks = 0; ks < 2; ++ks)                                         \
          acc[(MH) * 4 + m2][(NH) * 2 + n2] =                                  \
              __builtin_amdgcn_mfma_f32_16x16x32_bf16(                         \
                  av[m2][ks], bv[n2][ks], acc[(MH) * 4 + m2][(NH) * 2 + n2],   \
                  0, 0, 0);                                                    \
    __builtin_amdgcn_s_setprio(0);

  #define VM4 asm volatile("s_waitcnt vmcnt(4)" ::: "memory")
  #define VM2 asm volatile("s_waitcnt vmcnt(2)" ::: "memory")
  #define VM0 asm volatile("s_waitcnt vmcnt(0)" ::: "memory")
  #define BAR asm volatile("s_barrier" ::: "memory")
  #define PREMFMA                                                              \
    asm volatile("s_waitcnt lgkmcnt(0)" ::: "memory");                         \
    __builtin_amdgcn_sched_barrier(0)

  // prologue: K-tile 0's four pieces; Ah0,Bh0 must land (vmcnt(4))
  ISSUE_A(smem, 0, 0); ISSUE_B(smem, 0, 0); ISSUE_B(smem, 0, 1); ISSUE_A(smem, 0, 1);
  VM4; BAR;

  for (int kt = 0; kt < 12; ++kt) {
    const char* As = smem + (kt & 1) * 65536;
    const char* Bs = As + 32768;
    char* Ns = smem + ((kt + 1) & 1) * 65536;
    const int k1o = (kt + 1) * 64;
    const bool pf = (kt < 11);
    { // phase 0: (mh0, nh0) — needs Ah0,Bh0(kt); prefetch Ah0(kt+1)
      bf16x8 av[4][2], bv[2][2];
      DSR(0, 0)
      if (pf) { ISSUE_A(Ns, k1o, 0); VM4; } else { VM2; }
      BAR; PREMFMA;
      MFM(0, 0)
    }
    { // phase 1: (mh0, nh1) — needs Bh1(kt); prefetch Bh0(kt+1)
      bf16x8 av[4][2], bv[2][2];
      DSR(0, 1)
      if (pf) { ISSUE_B(Ns, k1o, 0); VM4; } else { VM0; }
      BAR; PREMFMA;
      MFM(0, 1)
    }
    { // phase 2: (mh1, nh0) — needs Ah1(kt); prefetch Bh1(kt+1)
      bf16x8 av[4][2], bv[2][2];
      DSR(1, 0)
      if (pf) ISSUE_B(Ns, k1o, 1);
      BAR; PREMFMA;
      MFM(1, 0)
    }
    { // phase 3: (mh1, nh1); prefetch Ah1(kt+1)
      bf16x8 av[4][2], bv[2][2];
      DSR(1, 1)
      if (pf) { ISSUE_A(Ns, k1o, 1); VM4; }
      BAR; PREMFMA;
      MFM(1, 1)
    }
  }
  #undef ISSUE_A
  #undef ISSUE_B
  #undef DSR
  #undef MFM

  __syncthreads();   // full drain; smem reusable for epilogue

  // ---- epilogue: bias, LN stats (cross-wave), a1/a2 dots, bf16 h store ----
  // row(acc[mi][.], reg) = row0 + (2mi+wm)*16 + rg*4 + reg
  // col(acc[.][ni])      = (4ni+wn)*16 + cl
  float* redS  = (float*)smem;                     // [256][4]
  float* redS2 = (float*)(smem + 4096);
  float* redP  = (float*)(smem + 8192);
  float* redC  = (float*)(smem + 12288);
  unsigned short* hs = (unsigned short*)(smem + 16384);   // [64][264]

  float bfn[4], gvn[4], bvn[4], a1n[4], a2n[4];
  #pragma unroll
  for (int ni = 0; ni < 4; ++ni) {
    const int c = (4 * ni + wn) * 16 + cl;
    bfn[ni] = bfc[n * HID + c];
    gvn[ni] = lng[n * HID + c];
    bvn[ni] = lnb[n * HID + c];
    a1n[ni] = aw[n * (2 * HID) + c];
    a2n[ni] = aw[n * (2 * HID) + HID + c];
  }

  // E1: per-row sum / sumsq (this wave covers 64 of 256 cols -> combine by wn)
  #pragma unroll
  for (int mi = 0; mi < 8; ++mi) {
    #pragma unroll
    for (int r = 0; r < 4; ++r) {
      float s = 0.f, s2 = 0.f;
      #pragma unroll
      for (int ni = 0; ni < 4; ++ni) {
        const float x = acc[mi][ni][r] + bfn[ni];
        acc[mi][ni][r] = x;
        s += x; s2 += x * x;
      }
      s = red16(s); s2 = red16(s2);
      if (cl == 0) {
        const int lr = (2 * mi + wm) * 16 + rg * 4 + r;
        redS [lr * 4 + wn] = s;
        redS2[lr * 4 + wn] = s2;
      }
    }
  }
  __syncthreads();

  // E2: normalize + a1/a2 dots
  #pragma unroll
  for (int mi = 0; mi < 8; ++mi) {
    #pragma unroll
    for (int r = 0; r < 4; ++r) {
      const int lr = (2 * mi + wm) * 16 + rg * 4 + r;
      const f32x4 sv  = *(const f32x4*)&redS [lr * 4];
      const f32x4 s2v = *(const f32x4*)&redS2[lr * 4];
      const float st  = sv.x + sv.y + sv.z + sv.w;
      const float s2t = s2v.x + s2v.y + s2v.z + s2v.w;
      const float mu  = st * (1.f / HID);
      const float var = s2t * (1.f / HID) - mu * mu;
      const float rs  = rsqrtf(var + 1e-5f);
      float pr = 0.f, pc = 0.f;
      #pragma unroll
      for (int ni = 0; ni < 4; ++ni) {
        const float hv = (acc[mi][ni][r] - mu) * rs * gvn[ni] + bvn[ni];
        acc[mi][ni][r] = hv;
        pr += hv * a1n[ni]; pc += hv * a2n[ni];
      }
      pr = red16(pr); pc = red16(pc);
      if (cl == 0) { redP[lr * 4 + wn] = pr; redC[lr * 4 + wn] = pc; }
    }
  }
  __syncthreads();
  if (t < 256) {
    const f32x4 pv = *(const f32x4*)&redP[t * 4];
    const f32x4 cv = *(const f32x4*)&redC[t * 4];
    sR[n * RTOT + row0 + t] = pv.x + pv.y + pv.z + pv.w;
    sC[n * RTOT + row0 + t] = cv.x + cv.y + cv.z + cv.w;
  }

  // E3: h store via [64][264] LDS bounce, 4 chunks (chunk c: rows c*64..+64;
  // every wave holds mi = 2c, 2c+1 for it, local row independent of c)
  unsigned short* hgb = hb + ((size_t)n * RTOT + row0) * HID;
  #pragma unroll
  for (int c = 0; c < 4; ++c) {
    #pragma unroll
    for (int m2 = 0; m2 < 2; ++m2) {
      const int mi = c * 2 + m2;
      #pragma unroll
      for (int r = 0; r < 4; ++r) {
        const int lr = (2 * m2 + wm) * 16 + rg * 4 + r;
        #pragma unroll
        for (int ni = 0; ni < 4; ++ni)
          hs[lr * 264 + (4 * ni + wn) * 16 + cl] = f2b(acc[mi][ni][r]);
      }
    }
    __syncthreads();
    #pragma unroll
    for (int i = 0; i < 4; ++i) {
      const int e  = i * 4096 + t * 8;
      const int lr = e >> 8, cc = e & 255;
      *(bf16x8*)&hgb[(size_t)(c * 64 + lr) * HID + cc] =
          *(const bf16x8*)&hs[lr * 264 + cc];
    }
    __syncthreads();
  }
}

// K2a: q[n,b,i] = m_i + log(sum_j exp(lrelu(c_i + r_j + ab) - m_i))
__global__ __launch_bounds__(256) void k2_lse(
    const float* __restrict__ sR, const float* __restrict__ sC,
    const float* __restrict__ ab, float* __restrict__ q)
{
  const int n  = blockIdx.x >> 7;
  const int b  = (blockIdx.x >> 3) & 15;
  const int ic = blockIdx.x & 7;
  const int t  = threadIdx.x;
  const int base = (n * BB + b) * LL;

  __shared__ float rl[LL];
  __shared__ float red[4];

  const float4 r4 = ((const float4*)(sR + base))[t];
  ((float4*)rl)[t] = r4;
  float tm = fmaxf(fmaxf(r4.x, r4.y), fmaxf(r4.z, r4.w));
  tm = waveReduceMax(tm);
  if ((t & 63) == 0) red[t >> 6] = tm;
  __syncthreads();
  const float rmax = fmaxf(fmaxf(red[0], red[1]), fmaxf(red[2], red[3]));

  const int i  = ic * 128 + (t >> 1);
  const int jh = t & 1;
  const float ci = sC[base + i] + ab[n];
  const float m = lrelu(ci + rmax);
  float z0 = 0.f, z1 = 0.f, z2 = 0.f, z3 = 0.f;
  #pragma unroll 4
  for (int j4 = jh * 128; j4 < jh * 128 + 128; ++j4) {
    const float4 rr = ((const float4*)rl)[j4];
    z0 += __expf(lrelu(ci + rr.x) - m);
    z1 += __expf(lrelu(ci + rr.y) - m);
    z2 += __expf(lrelu(ci + rr.z) - m);
    z3 += __expf(lrelu(ci + rr.w) - m);
  }
  float z = (z0 + z1) + (z2 + z3);
  z += __shfl_xor(z, 1, 64);
  if (!jh) q[base + i] = m + __logf(z);
}

// K23: fused colsum + weighted h-sum. 512 blocks: (n,b) x 8 j-chunks of 128.
__global__ __launch_bounds__(256) void k23_colw(
    const unsigned short* __restrict__ h, const float* __restrict__ sR,
    const float* __restrict__ sC, const float* __restrict__ ab,
    const float* __restrict__ q, float* __restrict__ partial)
{
  const int n  = blockIdx.x >> 7;
  const int b  = (blockIdx.x >> 3) & 15;
  const int jc = blockIdx.x & 7;
  const int t  = threadIdx.x;
  const int base = (n * BB + b) * LL;

  __shared__ float cls[LL];
  __shared__ float qls[LL];
  __shared__ float wl[128];
  __shared__ float red2[8][256];

  ((float4*)cls)[t] = ((const float4*)(sC + base))[t];
  ((float4*)qls)[t] = ((const float4*)(q + base))[t];
  __syncthreads();

  {
    const int j  = jc * 128 + (t >> 1);
    const int ih = t & 1;
    const float rj = sR[base + j] + ab[n];
    float z0 = 0.f, z1 = 0.f, z2 = 0.f, z3 = 0.f;
    #pragma unroll 4
    for (int i4 = ih * 128; i4 < ih * 128 + 128; ++i4) {
      const float4 cc = ((const float4*)cls)[i4];
      const float4 qq = ((const float4*)qls)[i4];
      z0 += __expf(lrelu(cc.x + rj) - qq.x);
      z1 += __expf(lrelu(cc.y + rj) - qq.y);
      z2 += __expf(lrelu(cc.z + rj) - qq.z);
      z3 += __expf(lrelu(cc.w + rj) - qq.w);
    }
    float z = (z0 + z1) + (z2 + z3);
    z += __shfl_xor(z, 1, 64);
    if (!ih) wl[t >> 1] = z * (1.f / LL);
  }
  __syncthreads();

  const int jl = t >> 5;
  const int cg = t & 31;
  const unsigned short* hp =
      h + ((size_t)n * RTOT + b * LL + jc * 128) * HID + cg * 8;
  float a0=0,a1=0,a2=0,a3=0,a4=0,a5=0,a6=0,a7=0;
  #pragma unroll 4
  for (int j = jl; j < 128; j += 8) {
    const bf16x8 v = *(const bf16x8*)(hp + (size_t)j * HID);
    const float w = wl[j];
    a0 = fmaf(w, b2f((unsigned short)v[0]), a0);
    a1 = fmaf(w, b2f((unsigned short)v[1]), a1);
    a2 = fmaf(w, b2f((unsigned short)v[2]), a2);
    a3 = fmaf(w, b2f((unsigned short)v[3]), a3);
    a4 = fmaf(w, b2f((unsigned short)v[4]), a4);
    a5 = fmaf(w, b2f((unsigned short)v[5]), a5);
    a6 = fmaf(w, b2f((unsigned short)v[6]), a6);
    a7 = fmaf(w, b2f((unsigned short)v[7]), a7);
  }
  red2[jl][cg*8+0]=a0; red2[jl][cg*8+1]=a1; red2[jl][cg*8+2]=a2; red2[jl][cg*8+3]=a3;
  red2[jl][cg*8+4]=a4; red2[jl][cg*8+5]=a5; red2[jl][cg*8+6]=a6; red2[jl][cg*8+7]=a7;
  __syncthreads();
  float s = 0.f;
  #pragma unroll
  for (int r = 0; r < 8; ++r) s += red2[r][t];
  partial[((n * BB + b) * 8 + jc) * 256 + t] = s;
}

// K4a: K-split partial GEMM (sent_raw reduce folded into staging)
__global__ __launch_bounds__(256) void k4_cat(
    const float* __restrict__ partial, const float* __restrict__ Wcat,
    float* __restrict__ pcat)
{
  const int kc = blockIdx.x / 3;
  const int oc = blockIdx.x % 3;
  const int t  = threadIdx.x;
  __shared__ float s[64][16];
  {
    const int kk = t >> 2, b4 = (t & 3) * 4;
    const int n = kc >> 2;
    const int c = (kc & 3) * 64 + kk;
    #pragma unroll
    for (int bi = 0; bi < 4; ++bi) {
      const int b = b4 + bi;
      const float* pb = partial + (size_t)((n * BB + b) * 8) * 256 + c;
      float v = 0.f;
      #pragma unroll
      for (int j = 0; j < 8; ++j) v += pb[j * 256];
      s[kk][b] = v;
    }
  }
  __syncthreads();
  const int o = oc * 256 + t;
  const float* W = Wcat + (size_t)(kc * 64) * OD + o;
  float acc[BB];
  #pragma unroll
  for (int b = 0; b < BB; ++b) acc[b] = 0.f;
  #pragma unroll 4
  for (int kk = 0; kk < 64; ++kk) {
    const float w = W[(size_t)kk * OD];
    const f32x4 s0 = *(const f32x4*)&s[kk][0];
    const f32x4 s1 = *(const f32x4*)&s[kk][4];
    const f32x4 s2 = *(const f32x4*)&s[kk][8];
    const f32x4 s3 = *(const f32x4*)&s[kk][12];
    acc[0]=fmaf(s0.x,w,acc[0]);  acc[1]=fmaf(s0.y,w,acc[1]);
    acc[2]=fmaf(s0.z,w,acc[2]);  acc[3]=fmaf(s0.w,w,acc[3]);
    acc[4]=fmaf(s1.x,w,acc[4]);  acc[5]=fmaf(s1.y,w,acc[5]);
    acc[6]=fmaf(s1.z,w,acc[6]);  acc[7]=fmaf(s1.w,w,acc[7]);
    acc[8]=fmaf(s2.x,w,acc[8]);  acc[9]=fmaf(s2.y,w,acc[9]);
    acc[10]=fmaf(s2.z,w,acc[10]); acc[11]=fmaf(s2.w,w,acc[11]);
    acc[12]=fmaf(s3.x,w,acc[12]); acc[13]=fmaf(s3.y,w,acc[13]);
    acc[14]=fmaf(s3.z,w,acc[14]); acc[15]=fmaf(s3.w,w,acc[15]);
  }
  float* P = pcat + (size_t)(kc * BB) * OD + o;
  #pragma unroll
  for (int b = 0; b < BB; ++b) P[(size_t)b * OD] = acc[b];
}

// K4b: sent = LN(bcat + sum_kc pcat)
__global__ __launch_bounds__(256) void k4_ln(
    const float* __restrict__ pcat, const float* __restrict__ bcat,
    const float* __restrict__ g, const float* __restrict__ be,
    float* __restrict__ sent, float* __restrict__ out_sent)
{
  const int b = blockIdx.x;
  const int t = threadIdx.x;
  __shared__ float red[4][2];
  float x[3];
  #pragma unroll
  for (int i = 0; i < 3; ++i) {
    const int o = i * 256 + t;
    float v = bcat[o];
    #pragma unroll
    for (int kc = 0; kc < 16; ++kc) v += pcat[(size_t)(kc * BB + b) * OD + o];
    x[i] = v;
  }
  float s  = x[0] + x[1] + x[2];
  float s2 = x[0]*x[0] + x[1]*x[1] + x[2]*x[2];
  s = waveReduceSum(s); s2 = waveReduceSum(s2);
  if ((t & 63) == 0) { red[t >> 6][0] = s; red[t >> 6][1] = s2; }
  __syncthreads();
  s  = red[0][0] + red[1][0] + red[2][0] + red[3][0];
  s2 = red[0][1] + red[1][1] + red[2][1] + red[3][1];
  const float mu  = s * (1.f / OD);
  const float var = s2 * (1.f / OD) - mu * mu;
  const float rs  = rsqrtf(var + 1e-5f);
  #pragma unroll
  for (int i = 0; i < 3; ++i) {
    const int o = i * 256 + t;
    const float y = (x[i] - mu) * rs * g[o] + be[o];
    sent[b * OD + o]     = y;
    out_sent[b * OD + o] = y;
  }
}

// K4c: K-split partials for the three output FCs.
__global__ __launch_bounds__(256) void k4_fcs(
    const float* __restrict__ sent, const float* __restrict__ Wfcs,
    float* __restrict__ pfcs)
{
  const int kc = blockIdx.x / 9;
  const int r  = blockIdx.x % 9;
  const int i  = r / 3, oc = r % 3;
  const int t  = threadIdx.x;
  __shared__ float s[64][16];
  {
    const int kk = t >> 2, b4 = (t & 3) * 4;
    #pragma unroll
    for (int bi = 0; bi < 4; ++bi)
      s[kk][b4 + bi] = sent[(b4 + bi) * OD + kc * 64 + kk];
  }
  __syncthreads();
  const int o = oc * 256 + t;
  const float* W = Wfcs + (size_t)i * OD * OD + (size_t)(kc * 64) * OD + o;
  float acc[BB];
  #pragma unroll
  for (int b = 0; b < BB; ++b) acc[b] = 0.f;
  #pragma unroll 4
  for (int kk = 0; kk < 64; ++kk) {
    const float w = W[(size_t)kk * OD];
    const f32x4 s0 = *(const f32x4*)&s[kk][0];
    const f32x4 s1 = *(const f32x4*)&s[kk][4];
    const f32x4 s2 = *(const f32x4*)&s[kk][8];
    const f32x4 s3 = *(const f32x4*)&s[kk][12];
    acc[0]=fmaf(s0.x,w,acc[0]);  acc[1]=fmaf(s0.y,w,acc[1]);
    acc[2]=fmaf(s0.z,w,acc[2]);  acc[3]=fmaf(s0.w,w,acc[3]);
    acc[4]=fmaf(s1.x,w,acc[4]);  acc[5]=fmaf(s1.y,w,acc[5]);
    acc[6]=fmaf(s1.z,w,acc[6]);  acc[7]=fmaf(s1.w,w,acc[7]);
    acc[8]=fmaf(s2.x,w,acc[8]);  acc[9]=fmaf(s2.y,w,acc[9]);
    acc[10]=fmaf(s2.z,w,acc[10]); acc[11]=fmaf(s2.w,w,acc[11]);
    acc[12]=fmaf(s3.x,w,acc[12]); acc[13]=fmaf(s3.y,w,acc[13]);
    acc[14]=fmaf(s3.z,w,acc[14]); acc[15]=fmaf(s3.w,w,acc[15]);
  }
  float* P = pfcs + (size_t)((kc * 3 + i) * BB) * OD + o;
  #pragma unroll
  for (int b = 0; b < BB; ++b) P[(size_t)b * OD] = acc[b];
}

// K4d: out[i][b][o] = bfcs[i,o] + sum_kc pfcs
__global__ __launch_bounds__(256) void k4_red(
    const float* __restrict__ pfcs, const float* __restrict__ bfcs,
    float* __restrict__ out)
{
  const int i = blockIdx.x >> 4;
  const int b = blockIdx.x & 15;
  const int t = threadIdx.x;
  #pragma unroll
  for (int oc = 0; oc < 3; ++oc) {
    const int o = oc * 256 + t;
    float v = bfcs[i * OD + o];
    #pragma unroll
    for (int kc = 0; kc < 12; ++kc)
      v += pfcs[(size_t)((kc * 3 + i) * BB + b) * OD + o];
    out[i * (BB * OD) + b * OD + o] = v;
  }
}

extern "C" void kernel_launch(void* const* d_in, const int* in_sizes, int n_in,
                              void* d_out, int out_size, void* d_ws, size_t ws_size,
                              hipStream_t stream)
{
  const float* T    = (const float*)d_in[0];
  const float* Wfc  = (const float*)d_in[1];
  const float* bfc  = (const float*)d_in[2];
  const float* lng  = (const float*)d_in[3];
  const float* lnb  = (const float*)d_in[4];
  const float* aw   = (const float*)d_in[5];
  const float* ab   = (const float*)d_in[6];
  const float* Wcat = (const float*)d_in[7];
  const float* bcat = (const float*)d_in[8];
  const float* lnOg = (const float*)d_in[9];
  const float* lnOb = (const float*)d_in[10];
  const float* Wfcs = (const float*)d_in[11];
  const float* bfcs = (const float*)d_in[12];
  float* out = (float*)d_out;

  char* W = (char*)d_ws;
  unsigned short* Tb  = (unsigned short*)W;                 // 25,165,824 B
  unsigned short* Wtb = (unsigned short*)(W + 25165824);    //  1,572,864 B
  unsigned short* hb  = (unsigned short*)(W + 26738688);    // 33,554,432 B
  float* sR      = (float*)(W + 60293120);
  float* sC      = sR + NH * RTOT;
  float* q       = sC + NH * RTOT;
  float* partial = q + NH * RTOT;                           // 131072 f
  float* sent    = partial + NH * BB * 8 * 256;
  float* pcat    = sent + BB * OD;
  float* pfcs    = pcat + 16 * BB * OD;

  kconv   <<<dim3(6336), dim3(256), 0, stream>>>(T, Wfc, Tb, Wtb);
  k1_mfma <<<dim3(256),  dim3(512), 0, stream>>>(Tb, Wtb, bfc, lng, lnb, aw, hb, sR, sC);
  k2_lse  <<<dim3(512),  dim3(256), 0, stream>>>(sR, sC, ab, q);
  k23_colw<<<dim3(512),  dim3(256), 0, stream>>>(hb, sR, sC, ab, q, partial);
  k4_cat  <<<dim3(48),   dim3(256), 0, stream>>>(partial, Wcat, pcat);
  k4_ln   <<<dim3(16),   dim3(256), 0, stream>>>(pcat, bcat, lnOg, lnOb, sent, out + 3 * BB * OD);
  k4_fcs  <<<dim3(108),  dim3(256), 0, stream>>>(sent, Wfcs, pfcs);
  k4_red  <<<dim3(48),   dim3(256), 0, stream>>>(pfcs, bfcs, out);
}

// Round 8
// 104.300 us; speedup vs baseline: 1.1324x; 1.1324x over previous
//
#include <hip/hip_runtime.h>
#include <math.h>

// MultiHeadGAT fused pipeline, round 8.
// k1: reverted to round-4 champion (256x256, BK=64, dbuf 2-phase, source-side
//     XOR swizzle (r&7)<<4, gll16 both operands) + epilogue pre-scales sR/sC
//     by log2(e). Tail: k2/k23 rewritten in log2 domain with per-row hoisting
//     (3 VALU + exp2 per element vs 6 VALU + mul + exp).

#define NH   4
#define TD   768
#define HID  256
#define OD   768
#define BB   16
#define LL   1024
#define RTOT (BB*LL)   // 16384 rows per head
#define L2E  1.4426950408889634f

typedef __attribute__((ext_vector_type(8))) short bf16x8;
typedef __attribute__((ext_vector_type(4))) float f32x4;

#if __has_builtin(__builtin_amdgcn_exp2f)
#define EXP2(x) __builtin_amdgcn_exp2f(x)
#else
#define EXP2(x) __expf((x) * 0.6931471805599453f)
#endif
#if __has_builtin(__builtin_amdgcn_logf)
#define LOG2(x) __builtin_amdgcn_logf(x)
#else
#define LOG2(x) (__logf(x) * L2E)
#endif

__device__ __forceinline__ float lrelu(float x) { return fmaxf(x, 0.01f * x); }

__device__ __forceinline__ float waveReduceSum(float v) {
  #pragma unroll
  for (int m = 1; m < 64; m <<= 1) v += __shfl_xor(v, m, 64);
  return v;
}
__device__ __forceinline__ float waveReduceMax(float v) {
  #pragma unroll
  for (int m = 1; m < 64; m <<= 1) v = fmaxf(v, __shfl_xor(v, m, 64));
  return v;
}
__device__ __forceinline__ float red16(float v) {   // reduce across 16-lane group
  v += __shfl_xor(v, 1, 64); v += __shfl_xor(v, 2, 64);
  v += __shfl_xor(v, 4, 64); v += __shfl_xor(v, 8, 64);
  return v;
}

__device__ __forceinline__ unsigned short f2b(float f) {  // f32 -> bf16 RNE
  union { float f; unsigned u; } v; v.f = f;
  unsigned u = v.u;
  return (unsigned short)((u + 0x7fffu + ((u >> 16) & 1u)) >> 16);
}
__device__ __forceinline__ float b2f(unsigned short h) {
  union { unsigned u; float f; } v; v.u = ((unsigned)h) << 16;
  return v.f;
}

__device__ __forceinline__ void gll16(const void* g, void* l) {
  __builtin_amdgcn_global_load_lds(
      (const __attribute__((address_space(1))) unsigned int*)g,
      (__attribute__((address_space(3))) unsigned int*)l, 16, 0, 0);
}

// ---- fused conversion kernel ----------------------------------------------
// blocks [0,6144): T fp32 -> bf16.  blocks [6144,6336): Wfc -> Wt bf16 (transp)
__global__ __launch_bounds__(256) void kconv(const float* __restrict__ T,
                                             const float* __restrict__ Wfc,
                                             unsigned short* __restrict__ Tb,
                                             unsigned short* __restrict__ Wtb) {
  __shared__ float tile[64][65];
  const int t = threadIdx.x;
  if (blockIdx.x < 6144) {
    const size_t i = ((size_t)blockIdx.x * 256 + t) * 8;
    const float4 a = *(const float4*)(T + i);
    const float4 b = *(const float4*)(T + i + 4);
    bf16x8 o;
    o[0] = (short)f2b(a.x); o[1] = (short)f2b(a.y);
    o[2] = (short)f2b(a.z); o[3] = (short)f2b(a.w);
    o[4] = (short)f2b(b.x); o[5] = (short)f2b(b.y);
    o[6] = (short)f2b(b.z); o[7] = (short)f2b(b.w);
    *(bf16x8*)(Tb + i) = o;
  } else {
    const int b2 = blockIdx.x - 6144;       // [0,192)
    const int ct = b2 & 3;
    const int kt = (b2 >> 2) % 12;
    const int n  = b2 / 48;
    #pragma unroll
    for (int i = 0; i < 16; ++i) {
      const int kl = i * 4 + (t >> 6), cl = t & 63;
      tile[kl][cl] =
          Wfc[(size_t)n * TD * HID + (size_t)(kt * 64 + kl) * HID + ct * 64 + cl];
    }
    __syncthreads();
    #pragma unroll
    for (int i = 0; i < 16; ++i) {
      const int cl = i * 4 + (t >> 6), kl = t & 63;
      Wtb[(size_t)n * HID * TD + (size_t)(ct * 64 + cl) * TD + kt * 64 + kl] =
          f2b(tile[kl][cl]);
    }
  }
}

// ---- K1: 256x256 MFMA GEMM + fused LN + a1/a2 dots (round-4 champion) ------
// grid = 4 heads x 64 m-blocks; 8 waves (2n x 4m), wave tile 64 rows x 128 cols.
// LDS: dbuf x (As[256][64] | Bs[256][64]) bf16 = 2 x 64KB = 128KB.
// Swizzle: LDS[r][kb] = G[r][kb ^ ((r&7)<<4)]; ds_read addr gets same XOR.
__global__ __launch_bounds__(512) void k1_mfma(
    const unsigned short* __restrict__ Tb,   // [16384][768] bf16
    const unsigned short* __restrict__ Wtb,  // [4][256][768] bf16 (W^T)
    const float* __restrict__ bfc, const float* __restrict__ lng,
    const float* __restrict__ lnb, const float* __restrict__ aw,
    unsigned short* __restrict__ hb,         // [4][16384][256] bf16
    float* __restrict__ sR, float* __restrict__ sC)
{
  const int n    = blockIdx.x >> 6;
  const int mb   = blockIdx.x & 63;
  const int t    = threadIdx.x;
  const int lane = t & 63;
  const int wq   = __builtin_amdgcn_readfirstlane(t >> 6);
  const int wm   = wq >> 1;          // 0..3  (m quarter)
  const int wn   = wq & 1;           // 0..1  (n half)
  const int cl   = lane & 15;
  const int rg   = lane >> 4;
  const int row0 = mb * 256;

  __shared__ __align__(16) char smem[131072];

  f32x4 acc[4][8];
  #pragma unroll
  for (int mi = 0; mi < 4; ++mi)
    #pragma unroll
    for (int ni = 0; ni < 8; ++ni) acc[mi][ni] = (f32x4){0.f, 0.f, 0.f, 0.f};

  const char* Tg = (const char*)Tb;
  const char* Wg = (const char*)(Wtb + (size_t)n * HID * TD);

  #define STAGE(buf, k0)                                                       \
    do {                                                                       \
      char* base_ = smem + (buf) * 65536;                                      \
      _Pragma("unroll")                                                        \
      for (int i_ = 0; i_ < 4; ++i_) {                                         \
        const int off_ = i_ * 8192 + t * 16;                                   \
        const int r_ = off_ >> 7, kb_ = off_ & 127;                            \
        const int kbs_ = kb_ ^ ((r_ & 7) << 4);                                \
        gll16(Tg + ((size_t)(row0 + r_) * TD + (k0)) * 2 + kbs_, base_ + off_);\
      }                                                                        \
      _Pragma("unroll")                                                        \
      for (int i_ = 0; i_ < 4; ++i_) {                                         \
        const int off_ = i_ * 8192 + t * 16;                                   \
        const int c_ = off_ >> 7, kb_ = off_ & 127;                            \
        const int kbs_ = kb_ ^ ((c_ & 7) << 4);                                \
        gll16(Wg + ((size_t)c_ * TD + (k0)) * 2 + kbs_, base_ + 32768 + off_); \
      }                                                                        \
    } while (0)

  STAGE(0, 0);
  __syncthreads();                 // drains vmcnt -> buf0 ready
  int cur = 0;
  for (int kt = 0; kt < 12; ++kt) {
    if (kt < 11) STAGE(cur ^ 1, (kt + 1) * 64);   // issue next-tile prefetch
    const char* As = smem + cur * 65536;
    const char* Bs = As + 32768;
    #pragma unroll
    for (int ks = 0; ks < 64; ks += 32) {
      bf16x8 av[4], bv[8];
      const int kk2 = (ks + rg * 8) * 2;
      #pragma unroll
      for (int mi = 0; mi < 4; ++mi) {
        const int row = wm * 64 + mi * 16 + cl;
        av[mi] = *(const bf16x8*)(As + row * 128 + (kk2 ^ ((row & 7) << 4)));
      }
      #pragma unroll
      for (int ni = 0; ni < 8; ++ni) {
        const int row = wn * 128 + ni * 16 + cl;
        bv[ni] = *(const bf16x8*)(Bs + row * 128 + (kk2 ^ ((row & 7) << 4)));
      }
      #pragma unroll
      for (int mi = 0; mi < 4; ++mi)
        #pragma unroll
        for (int ni = 0; ni < 8; ++ni)
          acc[mi][ni] = __builtin_amdgcn_mfma_f32_16x16x32_bf16(
              av[mi], bv[ni], acc[mi][ni], 0, 0, 0);
    }
    __syncthreads();               // reads of cur done + prefetch landed
    cur ^= 1;
  }
  #undef STAGE

  // ---- epilogue ----
  unsigned short* hs = (unsigned short*)smem;        // [64][264] per chunk
  float* redS  = (float*)(smem + 36864);             // [256][2]
  float* redS2 = (float*)(smem + 38912);
  float* redP  = (float*)(smem + 40960);
  float* redC  = (float*)(smem + 43008);

  float bfn[8], gvn[8], bvn[8], a1n[8], a2n[8];
  #pragma unroll
  for (int ni = 0; ni < 8; ++ni) {
    const int c = wn * 128 + ni * 16 + cl;
    bfn[ni] = bfc[n * HID + c];
    gvn[ni] = lng[n * HID + c];
    bvn[ni] = lnb[n * HID + c];
    a1n[ni] = aw[n * (2 * HID) + c];
    a2n[ni] = aw[n * (2 * HID) + HID + c];
  }

  // E1: per-row sum / sumsq (this wave covers half the row -> LDS combine)
  #pragma unroll
  for (int mi = 0; mi < 4; ++mi) {
    #pragma unroll
    for (int r = 0; r < 4; ++r) {
      float s = 0.f, s2 = 0.f;
      #pragma unroll
      for (int ni = 0; ni < 8; ++ni) {
        const float x = acc[mi][ni][r] + bfn[ni];
        acc[mi][ni][r] = x;
        s += x; s2 += x * x;
      }
      s = red16(s); s2 = red16(s2);
      if (cl == 0) {
        const int row = wm * 64 + mi * 16 + rg * 4 + r;
        redS [row * 2 + wn] = s;
        redS2[row * 2 + wn] = s2;
      }
    }
  }
  __syncthreads();

  // E2: normalize, a1/a2 dots
  #pragma unroll
  for (int mi = 0; mi < 4; ++mi) {
    #pragma unroll
    for (int r = 0; r < 4; ++r) {
      const int row = wm * 64 + mi * 16 + rg * 4 + r;
      const float st  = redS [row * 2] + redS [row * 2 + 1];
      const float s2t = redS2[row * 2] + redS2[row * 2 + 1];
      const float mu  = st * (1.f / HID);
      const float var = s2t * (1.f / HID) - mu * mu;
      const float rs  = rsqrtf(var + 1e-5f);
      float pr = 0.f, pc = 0.f;
      #pragma unroll
      for (int ni = 0; ni < 8; ++ni) {
        const float hv = (acc[mi][ni][r] - mu) * rs * gvn[ni] + bvn[ni];
        acc[mi][ni][r] = hv;
        pr += hv * a1n[ni]; pc += hv * a2n[ni];
      }
      pr = red16(pr); pc = red16(pc);
      if (cl == 0) { redP[row * 2 + wn] = pr; redC[row * 2 + wn] = pc; }
    }
  }
  __syncthreads();
  if (t < 256) {
    // pre-scale by log2(e): downstream softmax runs in log2 domain
    sR[n * RTOT + row0 + t] = (redP[t * 2] + redP[t * 2 + 1]) * L2E;
    sC[n * RTOT + row0 + t] = (redC[t * 2] + redC[t * 2 + 1]) * L2E;
  }

  // E3: h store via LDS bounce, 4 chunks (chunk c = fragment-row group mi=c)
  unsigned short* hgb = hb + ((size_t)n * RTOT + row0) * HID;
  #pragma unroll
  for (int c = 0; c < 4; ++c) {
    #pragma unroll
    for (int ni = 0; ni < 8; ++ni)
      #pragma unroll
      for (int r = 0; r < 4; ++r) {
        const int lr  = wm * 16 + rg * 4 + r;
        const int col = wn * 128 + ni * 16 + cl;
        hs[lr * 264 + col] = f2b(acc[c][ni][r]);
      }
    __syncthreads();
    #pragma unroll
    for (int i = 0; i < 4; ++i) {
      const int idx = i * 4096 + t * 8;
      const int lr = idx >> 8, cc = idx & 255;
      const int grow = (lr >> 4) * 64 + c * 16 + (lr & 15);
      *(bf16x8*)&hgb[(size_t)grow * HID + cc] = *(const bf16x8*)&hs[lr * 264 + cc];
    }
    __syncthreads();
  }
}

// K2a (log2 domain): q'[i] = m' + log2(sum_j 2^(lrelu(c'_i + r'_j) - m'))
// inner: max((c'-m') + r', (0.01c'-m') + 0.01r') == lrelu(c'+r') - m'
__global__ __launch_bounds__(256) void k2_lse(
    const float* __restrict__ sR, const float* __restrict__ sC,
    const float* __restrict__ ab, float* __restrict__ q)
{
  const int n  = blockIdx.x >> 7;
  const int b  = (blockIdx.x >> 3) & 15;
  const int ic = blockIdx.x & 7;
  const int t  = threadIdx.x;
  const int base = (n * BB + b) * LL;

  __shared__ float rl[LL];
  __shared__ float r01l[LL];
  __shared__ float red[4];

  const float4 r4 = ((const float4*)(sR + base))[t];
  ((float4*)rl)[t] = r4;
  float4 r01;
  r01.x = 0.01f * r4.x; r01.y = 0.01f * r4.y;
  r01.z = 0.01f * r4.z; r01.w = 0.01f * r4.w;
  ((float4*)r01l)[t] = r01;
  float tm = fmaxf(fmaxf(r4.x, r4.y), fmaxf(r4.z, r4.w));
  tm = waveReduceMax(tm);
  if ((t & 63) == 0) red[t >> 6] = tm;
  __syncthreads();
  const float rmax = fmaxf(fmaxf(red[0], red[1]), fmaxf(red[2], red[3]));

  const int i  = ic * 128 + (t >> 1);
  const int jh = t & 1;
  const float ci = sC[base + i] + ab[n] * L2E;
  const float m  = lrelu(ci + rmax);
  const float a1 = ci - m;
  const float a2 = 0.01f * ci - m;
  float z0 = 0.f, z1 = 0.f, z2 = 0.f, z3 = 0.f;
  #pragma unroll 4
  for (int j4 = jh * 128; j4 < jh * 128 + 128; ++j4) {
    const float4 rr = ((const float4*)rl)[j4];
    const float4 r0 = ((const float4*)r01l)[j4];
    z0 += EXP2(fmaxf(a1 + rr.x, a2 + r0.x));
    z1 += EXP2(fmaxf(a1 + rr.y, a2 + r0.y));
    z2 += EXP2(fmaxf(a1 + rr.z, a2 + r0.z));
    z3 += EXP2(fmaxf(a1 + rr.w, a2 + r0.w));
  }
  float z = (z0 + z1) + (z2 + z3);
  z += __shfl_xor(z, 1, 64);
  if (!jh) q[base + i] = m + LOG2(z);
}

// K23 (log2 domain): fused colsum + weighted h-sum.
// phase1 inner: max((c'-q') + r', (0.01c'-q') + 0.01r') == lrelu(c'+r') - q'
__global__ __launch_bounds__(256) void k23_colw(
    const unsigned short* __restrict__ h, const float* __restrict__ sR,
    const float* __restrict__ sC, const float* __restrict__ ab,
    const float* __restrict__ q, float* __restrict__ partial)
{
  const int n  = blockIdx.x >> 7;
  const int b  = (blockIdx.x >> 3) & 15;
  const int jc = blockIdx.x & 7;
  const int t  = threadIdx.x;
  const int base = (n * BB + b) * LL;

  __shared__ float cls1[LL];
  __shared__ float cls2[LL];
  __shared__ float wl[128];
  __shared__ float red2[8][256];

  {
    const float4 c4 = ((const float4*)(sC + base))[t];
    const float4 q4 = ((const float4*)(q + base))[t];
    float4 v1, v2;
    v1.x = c4.x - q4.x; v2.x = 0.01f * c4.x - q4.x;
    v1.y = c4.y - q4.y; v2.y = 0.01f * c4.y - q4.y;
    v1.z = c4.z - q4.z; v2.z = 0.01f * c4.z - q4.z;
    v1.w = c4.w - q4.w; v2.w = 0.01f * c4.w - q4.w;
    ((float4*)cls1)[t] = v1;
    ((float4*)cls2)[t] = v2;
  }
  __syncthreads();

  // phase 1: wcol for 128 j's; 2 threads per j (i split in halves)
  {
    const int j  = jc * 128 + (t >> 1);
    const int ih = t & 1;
    const float rj  = sR[base + j] + ab[n] * L2E;
    const float r01 = 0.01f * rj;
    float z0 = 0.f, z1 = 0.f, z2 = 0.f, z3 = 0.f;
    #pragma unroll 4
    for (int i4 = ih * 128; i4 < ih * 128 + 128; ++i4) {
      const float4 c1 = ((const float4*)cls1)[i4];
      const float4 c2 = ((const float4*)cls2)[i4];
      z0 += EXP2(fmaxf(c1.x + rj, c2.x + r01));
      z1 += EXP2(fmaxf(c1.y + rj, c2.y + r01));
      z2 += EXP2(fmaxf(c1.z + rj, c2.z + r01));
      z3 += EXP2(fmaxf(c1.w + rj, c2.w + r01));
    }
    float z = (z0 + z1) + (z2 + z3);
    z += __shfl_xor(z, 1, 64);
    if (!ih) wl[t >> 1] = z * (1.f / LL);
  }
  __syncthreads();

  // phase 2: weighted column sum over the 128 j's
  const int jl = t >> 5;
  const int cg = t & 31;
  const unsigned short* hp =
      h + ((size_t)n * RTOT + b * LL + jc * 128) * HID + cg * 8;
  float a0=0,a1=0,a2=0,a3=0,a4=0,a5=0,a6=0,a7=0;
  #pragma unroll 4
  for (int j = jl; j < 128; j += 8) {
    const bf16x8 v = *(const bf16x8*)(hp + (size_t)j * HID);
    const float w = wl[j];
    a0 = fmaf(w, b2f((unsigned short)v[0]), a0);
    a1 = fmaf(w, b2f((unsigned short)v[1]), a1);
    a2 = fmaf(w, b2f((unsigned short)v[2]), a2);
    a3 = fmaf(w, b2f((unsigned short)v[3]), a3);
    a4 = fmaf(w, b2f((unsigned short)v[4]), a4);
    a5 = fmaf(w, b2f((unsigned short)v[5]), a5);
    a6 = fmaf(w, b2f((unsigned short)v[6]), a6);
    a7 = fmaf(w, b2f((unsigned short)v[7]), a7);
  }
  red2[jl][cg*8+0]=a0; red2[jl][cg*8+1]=a1; red2[jl][cg*8+2]=a2; red2[jl][cg*8+3]=a3;
  red2[jl][cg*8+4]=a4; red2[jl][cg*8+5]=a5; red2[jl][cg*8+6]=a6; red2[jl][cg*8+7]=a7;
  __syncthreads();
  float s = 0.f;
  #pragma unroll
  for (int r = 0; r < 8; ++r) s += red2[r][t];
  partial[((n * BB + b) * 8 + jc) * 256 + t] = s;
}

// K4a: K-split partial GEMM (sent_raw reduce folded into staging)
__global__ __launch_bounds__(256) void k4_cat(
    const float* __restrict__ partial, const float* __restrict__ Wcat,
    float* __restrict__ pcat)
{
  const int kc = blockIdx.x / 3;
  const int oc = blockIdx.x % 3;
  const int t  = threadIdx.x;
  __shared__ float s[64][16];
  {
    const int kk = t >> 2, b4 = (t & 3) * 4;
    const int n = kc >> 2;
    const int c = (kc & 3) * 64 + kk;
    #pragma unroll
    for (int bi = 0; bi < 4; ++bi) {
      const int b = b4 + bi;
      const float* pb = partial + (size_t)((n * BB + b) * 8) * 256 + c;
      float v = 0.f;
      #pragma unroll
      for (int j = 0; j < 8; ++j) v += pb[j * 256];
      s[kk][b] = v;
    }
  }
  __syncthreads();
  const int o = oc * 256 + t;
  const float* W = Wcat + (size_t)(kc * 64) * OD + o;
  float acc[BB];
  #pragma unroll
  for (int b = 0; b < BB; ++b) acc[b] = 0.f;
  #pragma unroll 4
  for (int kk = 0; kk < 64; ++kk) {
    const float w = W[(size_t)kk * OD];
    const f32x4 s0 = *(const f32x4*)&s[kk][0];
    const f32x4 s1 = *(const f32x4*)&s[kk][4];
    const f32x4 s2 = *(const f32x4*)&s[kk][8];
    const f32x4 s3 = *(const f32x4*)&s[kk][12];
    acc[0]=fmaf(s0.x,w,acc[0]);  acc[1]=fmaf(s0.y,w,acc[1]);
    acc[2]=fmaf(s0.z,w,acc[2]);  acc[3]=fmaf(s0.w,w,acc[3]);
    acc[4]=fmaf(s1.x,w,acc[4]);  acc[5]=fmaf(s1.y,w,acc[5]);
    acc[6]=fmaf(s1.z,w,acc[6]);  acc[7]=fmaf(s1.w,w,acc[7]);
    acc[8]=fmaf(s2.x,w,acc[8]);  acc[9]=fmaf(s2.y,w,acc[9]);
    acc[10]=fmaf(s2.z,w,acc[10]); acc[11]=fmaf(s2.w,w,acc[11]);
    acc[12]=fmaf(s3.x,w,acc[12]); acc[13]=fmaf(s3.y,w,acc[13]);
    acc[14]=fmaf(s3.z,w,acc[14]); acc[15]=fmaf(s3.w,w,acc[15]);
  }
  float* P = pcat + (size_t)(kc * BB) * OD + o;
  #pragma unroll
  for (int b = 0; b < BB; ++b) P[(size_t)b * OD] = acc[b];
}

// K4b: sent = LN(bcat + sum_kc pcat)
__global__ __launch_bounds__(256) void k4_ln(
    const float* __restrict__ pcat, const float* __restrict__ bcat,
    const float* __restrict__ g, const float* __restrict__ be,
    float* __restrict__ sent, float* __restrict__ out_sent)
{
  const int b = blockIdx.x;
  const int t = threadIdx.x;
  __shared__ float red[4][2];
  float x[3];
  #pragma unroll
  for (int i = 0; i < 3; ++i) {
    const int o = i * 256 + t;
    float v = bcat[o];
    #pragma unroll
    for (int kc = 0; kc < 16; ++kc) v += pcat[(size_t)(kc * BB + b) * OD + o];
    x[i] = v;
  }
  float s  = x[0] + x[1] + x[2];
  float s2 = x[0]*x[0] + x[1]*x[1] + x[2]*x[2];
  s = waveReduceSum(s); s2 = waveReduceSum(s2);
  if ((t & 63) == 0) { red[t >> 6][0] = s; red[t >> 6][1] = s2; }
  __syncthreads();
  s  = red[0][0] + red[1][0] + red[2][0] + red[3][0];
  s2 = red[0][1] + red[1][1] + red[2][1] + red[3][1];
  const float mu  = s * (1.f / OD);
  const float var = s2 * (1.f / OD) - mu * mu;
  const float rs  = rsqrtf(var + 1e-5f);
  #pragma unroll
  for (int i = 0; i < 3; ++i) {
    const int o = i * 256 + t;
    const float y = (x[i] - mu) * rs * g[o] + be[o];
    sent[b * OD + o]     = y;
    out_sent[b * OD + o] = y;
  }
}

// K4c: K-split partials for the three output FCs.
__global__ __launch_bounds__(256) void k4_fcs(
    const float* __restrict__ sent, const float* __restrict__ Wfcs,
    float* __restrict__ pfcs)
{
  const int kc = blockIdx.x / 9;
  const int r  = blockIdx.x % 9;
  const int i  = r / 3, oc = r % 3;
  const int t  = threadIdx.x;
  __shared__ float s[64][16];
  {
    const int kk = t >> 2, b4 = (t & 3) * 4;
    #pragma unroll
    for (int bi = 0; bi < 4; ++bi)
      s[kk][b4 + bi] = sent[(b4 + bi) * OD + kc * 64 + kk];
  }
  __syncthreads();
  const int o = oc * 256 + t;
  const float* W = Wfcs + (size_t)i * OD * OD + (size_t)(kc * 64) * OD + o;
  float acc[BB];
  #pragma unroll
  for (int b = 0; b < BB; ++b) acc[b] = 0.f;
  #pragma unroll 4
  for (int kk = 0; kk < 64; ++kk) {
    const float w = W[(size_t)kk * OD];
    const f32x4 s0 = *(const f32x4*)&s[kk][0];
    const f32x4 s1 = *(const f32x4*)&s[kk][4];
    const f32x4 s2 = *(const f32x4*)&s[kk][8];
    const f32x4 s3 = *(const f32x4*)&s[kk][12];
    acc[0]=fmaf(s0.x,w,acc[0]);  acc[1]=fmaf(s0.y,w,acc[1]);
    acc[2]=fmaf(s0.z,w,acc[2]);  acc[3]=fmaf(s0.w,w,acc[3]);
    acc[4]=fmaf(s1.x,w,acc[4]);  acc[5]=fmaf(s1.y,w,acc[5]);
    acc[6]=fmaf(s1.z,w,acc[6]);  acc[7]=fmaf(s1.w,w,acc[7]);
    acc[8]=fmaf(s2.x,w,acc[8]);  acc[9]=fmaf(s2.y,w,acc[9]);
    acc[10]=fmaf(s2.z,w,acc[10]); acc[11]=fmaf(s2.w,w,acc[11]);
    acc[12]=fmaf(s3.x,w,acc[12]); acc[13]=fmaf(s3.y,w,acc[13]);
    acc[14]=fmaf(s3.z,w,acc[14]); acc[15]=fmaf(s3.w,w,acc[15]);
  }
  float* P = pfcs + (size_t)((kc * 3 + i) * BB) * OD + o;
  #pragma unroll
  for (int b = 0; b < BB; ++b) P[(size_t)b * OD] = acc[b];
}

// K4d: out[i][b][o] = bfcs[i,o] + sum_kc pfcs
__global__ __launch_bounds__(256) void k4_red(
    const float* __restrict__ pfcs, const float* __restrict__ bfcs,
    float* __restrict__ out)
{
  const int i = blockIdx.x >> 4;
  const int b = blockIdx.x & 15;
  const int t = threadIdx.x;
  #pragma unroll
  for (int oc = 0; oc < 3; ++oc) {
    const int o = oc * 256 + t;
    float v = bfcs[i * OD + o];
    #pragma unroll
    for (int kc = 0; kc < 12; ++kc)
      v += pfcs[(size_t)((kc * 3 + i) * BB + b) * OD + o];
    out[i * (BB * OD) + b * OD + o] = v;
  }
}

extern "C" void kernel_launch(void* const* d_in, const int* in_sizes, int n_in,
                              void* d_out, int out_size, void* d_ws, size_t ws_size,
                              hipStream_t stream)
{
  const float* T    = (const float*)d_in[0];
  const float* Wfc  = (const float*)d_in[1];
  const float* bfc  = (const float*)d_in[2];
  const float* lng  = (const float*)d_in[3];
  const float* lnb  = (const float*)d_in[4];
  const float* aw   = (const float*)d_in[5];
  const float* ab   = (const float*)d_in[6];
  const float* Wcat = (const float*)d_in[7];
  const float* bcat = (const float*)d_in[8];
  const float* lnOg = (const float*)d_in[9];
  const float* lnOb = (const float*)d_in[10];
  const float* Wfcs = (const float*)d_in[11];
  const float* bfcs = (const float*)d_in[12];
  float* out = (float*)d_out;

  char* W = (char*)d_ws;
  unsigned short* Tb  = (unsigned short*)W;                 // 25,165,824 B
  unsigned short* Wtb = (unsigned short*)(W + 25165824);    //  1,572,864 B
  unsigned short* hb  = (unsigned short*)(W + 26738688);    // 33,554,432 B
  float* sR      = (float*)(W + 60293120);
  float* sC      = sR + NH * RTOT;
  float* q       = sC + NH * RTOT;
  float* partial = q + NH * RTOT;                           // 131072 f
  float* sent    = partial + NH * BB * 8 * 256;
  float* pcat    = sent + BB * OD;
  float* pfcs    = pcat + 16 * BB * OD;

  kconv   <<<dim3(6336), dim3(256), 0, stream>>>(T, Wfc, Tb, Wtb);
  k1_mfma <<<dim3(256),  dim3(512), 0, stream>>>(Tb, Wtb, bfc, lng, lnb, aw, hb, sR, sC);
  k2_lse  <<<dim3(512),  dim3(256), 0, stream>>>(sR, sC, ab, q);
  k23_colw<<<dim3(512),  dim3(256), 0, stream>>>(hb, sR, sC, ab, q, partial);
  k4_cat  <<<dim3(48),   dim3(256), 0, stream>>>(partial, Wcat, pcat);
  k4_ln   <<<dim3(16),   dim3(256), 0, stream>>>(pcat, bcat, lnOg, lnOb, sent, out + 3 * BB * OD);
  k4_fcs  <<<dim3(108),  dim3(256), 0, stream>>>(sent, Wfcs, pfcs);
  k4_red  <<<dim3(48),   dim3(256), 0, stream>>>(pfcs, bfcs, out);
}

// Round 9
// 103.262 us; speedup vs baseline: 1.1438x; 1.0101x over previous
//
#include <hip/hip_runtime.h>
#include <math.h>

// MultiHeadGAT fused pipeline, round 9.
// k1: R4-champion schedule (256x256, BK=64, dbuf 2-phase, (r&7)<<4 swizzle)
//     with T->bf16 conversion FUSED into A-staging (reg-stage fp32 ->
//     v_cvt_pk_bf16_f32 -> swizzled ds_write_b128). B via global_load_lds.
//     kconv reduced to W-transpose only. Tail = R8 (log2-domain softmax).

#define NH   4
#define TD   768
#define HID  256
#define OD   768
#define BB   16
#define LL   1024
#define RTOT (BB*LL)   // 16384 rows per head
#define L2E  1.4426950408889634f

typedef __attribute__((ext_vector_type(8))) short bf16x8;
typedef __attribute__((ext_vector_type(4))) float f32x4;

#if __has_builtin(__builtin_amdgcn_exp2f)
#define EXP2(x) __builtin_amdgcn_exp2f(x)
#else
#define EXP2(x) __expf((x) * 0.6931471805599453f)
#endif
#if __has_builtin(__builtin_amdgcn_logf)
#define LOG2(x) __builtin_amdgcn_logf(x)
#else
#define LOG2(x) (__logf(x) * L2E)
#endif

__device__ __forceinline__ float lrelu(float x) { return fmaxf(x, 0.01f * x); }

__device__ __forceinline__ float waveReduceSum(float v) {
  #pragma unroll
  for (int m = 1; m < 64; m <<= 1) v += __shfl_xor(v, m, 64);
  return v;
}
__device__ __forceinline__ float waveReduceMax(float v) {
  #pragma unroll
  for (int m = 1; m < 64; m <<= 1) v = fmaxf(v, __shfl_xor(v, m, 64));
  return v;
}
__device__ __forceinline__ float red16(float v) {   // reduce across 16-lane group
  v += __shfl_xor(v, 1, 64); v += __shfl_xor(v, 2, 64);
  v += __shfl_xor(v, 4, 64); v += __shfl_xor(v, 8, 64);
  return v;
}

__device__ __forceinline__ unsigned short f2b(float f) {  // f32 -> bf16 RNE
  union { float f; unsigned u; } v; v.f = f;
  unsigned u = v.u;
  return (unsigned short)((u + 0x7fffu + ((u >> 16) & 1u)) >> 16);
}
__device__ __forceinline__ float b2f(unsigned short h) {
  union { unsigned u; float f; } v; v.u = ((unsigned)h) << 16;
  return v.f;
}
// packed f32x2 -> bf16x2 (RNE), single VALU op
__device__ __forceinline__ unsigned cvtpk(float lo, float hi) {
  unsigned r;
  asm("v_cvt_pk_bf16_f32 %0, %1, %2" : "=v"(r) : "v"(lo), "v"(hi));
  return r;
}

__device__ __forceinline__ void gll16(const void* g, void* l) {
  __builtin_amdgcn_global_load_lds(
      (const __attribute__((address_space(1))) unsigned int*)g,
      (__attribute__((address_space(3))) unsigned int*)l, 16, 0, 0);
}

// ---- conversion kernel: W only ---------------------------------------------
// Wfc fp32 [n][k=768][c=256] -> bf16 transposed Wt [n][c=256][k=768]
__global__ __launch_bounds__(256) void kconv_w(const float* __restrict__ src,
                                               unsigned short* __restrict__ dst) {
  __shared__ float tile[64][65];
  const int t  = threadIdx.x;
  const int ct = blockIdx.x & 3;
  const int kt = (blockIdx.x >> 2) % 12;
  const int n  = blockIdx.x / 48;
  #pragma unroll
  for (int i = 0; i < 16; ++i) {
    const int kl = i * 4 + (t >> 6), cl = t & 63;
    tile[kl][cl] =
        src[(size_t)n * TD * HID + (size_t)(kt * 64 + kl) * HID + ct * 64 + cl];
  }
  __syncthreads();
  #pragma unroll
  for (int i = 0; i < 16; ++i) {
    const int cl = i * 4 + (t >> 6), kl = t & 63;
    dst[(size_t)n * HID * TD + (size_t)(ct * 64 + cl) * TD + kt * 64 + kl] =
        f2b(tile[kl][cl]);
  }
}

// ---- K1: 256x256 MFMA GEMM + fused T-conversion + LN + a1/a2 dots ----------
// grid = 4 heads x 64 m-blocks; 8 waves (2n x 4m), wave tile 64 rows x 128 cols.
// LDS: dbuf x (As[256][64] | Bs[256][64]) bf16 = 2 x 64KB = 128KB.
// A: reg-staged from fp32 T (prefetched 1 K-step ahead), cvt_pk, swizzled
//    ds_write_b128. B: global_load_lds, pre-swizzled source.
// Swizzle: LDS[r][kb ^ ((r&7)<<4)] = G[r][kb]; ds_read applies same XOR.
__global__ __launch_bounds__(512) void k1_mfma(
    const float* __restrict__ T,             // [16384][768] fp32
    const unsigned short* __restrict__ Wtb,  // [4][256][768] bf16 (W^T)
    const float* __restrict__ bfc, const float* __restrict__ lng,
    const float* __restrict__ lnb, const float* __restrict__ aw,
    unsigned short* __restrict__ hb,         // [4][16384][256] bf16
    float* __restrict__ sR, float* __restrict__ sC)
{
  const int n    = blockIdx.x >> 6;
  const int mb   = blockIdx.x & 63;
  const int t    = threadIdx.x;
  const int lane = t & 63;
  const int wq   = __builtin_amdgcn_readfirstlane(t >> 6);
  const int wm   = wq >> 1;          // 0..3  (m quarter)
  const int wn   = wq & 1;           // 0..1  (n half)
  const int cl   = lane & 15;
  const int rg   = lane >> 4;
  const int row0 = mb * 256;

  __shared__ __align__(16) char smem[131072];

  f32x4 acc[4][8];
  #pragma unroll
  for (int mi = 0; mi < 4; ++mi)
    #pragma unroll
    for (int ni = 0; ni < 8; ++ni) acc[mi][ni] = (f32x4){0.f, 0.f, 0.f, 0.f};

  const char* Wg = (const char*)(Wtb + (size_t)n * HID * TD);

  // A reg-stage: 4 rows/thread (row = j*64 + t>>3), 8 fp32 (kcol (t&7)*8)
  #define LDA(r, k0)                                                           \
    do {                                                                       \
      _Pragma("unroll")                                                        \
      for (int j_ = 0; j_ < 4; ++j_) {                                         \
        const float* p_ = T + (size_t)(row0 + j_ * 64 + (t >> 3)) * TD +       \
                          (k0) + (t & 7) * 8;                                  \
        r[2 * j_]     = *(const float4*)p_;                                    \
        r[2 * j_ + 1] = *(const float4*)(p_ + 4);                              \
      }                                                                        \
    } while (0)

  // A cvt_pk + swizzled ds_write_b128 into buf
  #define WRA(buf, r)                                                          \
    do {                                                                       \
      char* ab_ = smem + (buf) * 65536;                                        \
      _Pragma("unroll")                                                        \
      for (int j_ = 0; j_ < 4; ++j_) {                                         \
        const int row_ = j_ * 64 + (t >> 3);                                   \
        const int kb_  = (t & 7) * 16;                                         \
        uint4 p_;                                                              \
        p_.x = cvtpk(r[2 * j_].x,     r[2 * j_].y);                            \
        p_.y = cvtpk(r[2 * j_].z,     r[2 * j_].w);                            \
        p_.z = cvtpk(r[2 * j_ + 1].x, r[2 * j_ + 1].y);                        \
        p_.w = cvtpk(r[2 * j_ + 1].z, r[2 * j_ + 1].w);                        \
        *(uint4*)(ab_ + row_ * 128 + (kb_ ^ ((row_ & 7) << 4))) = p_;          \
      }                                                                        \
    } while (0)

  // B stage: 32KB via global_load_lds, pre-swizzled source
  #define STAGE_B(buf, k0)                                                     \
    do {                                                                       \
      char* bb_ = smem + (buf) * 65536 + 32768;                                \
      _Pragma("unroll")                                                        \
      for (int i_ = 0; i_ < 4; ++i_) {                                         \
        const int off_ = i_ * 8192 + t * 16;                                   \
        const int c_ = off_ >> 7, kb_ = off_ & 127;                            \
        const int kbs_ = kb_ ^ ((c_ & 7) << 4);                                \
        gll16(Wg + ((size_t)c_ * TD + (k0)) * 2 + kbs_, bb_ + off_);           \
      }                                                                        \
    } while (0)

  float4 rA[8];
  // prologue: tile0 staged (A written, B issued), tile1 A in regs
  LDA(rA, 0);
  STAGE_B(0, 0);
  WRA(0, rA);
  LDA(rA, 64);
  __syncthreads();                 // drains vmcnt (B0) + lgkm (A0 writes)

  int cur = 0;
  for (int kt = 0; kt < 12; ++kt) {
    if (kt < 11) {
      STAGE_B(cur ^ 1, (kt + 1) * 64);   // async B prefetch
      WRA(cur ^ 1, rA);                  // A tile kt+1 from regs
      if (kt < 10) LDA(rA, (kt + 2) * 64);   // A tile kt+2 into regs
    }
    const char* As = smem + cur * 65536;
    const char* Bs = As + 32768;
    #pragma unroll
    for (int ks = 0; ks < 64; ks += 32) {
      bf16x8 av[4], bv[8];
      const int kk2 = (ks + rg * 8) * 2;
      #pragma unroll
      for (int mi = 0; mi < 4; ++mi) {
        const int row = wm * 64 + mi * 16 + cl;
        av[mi] = *(const bf16x8*)(As + row * 128 + (kk2 ^ ((row & 7) << 4)));
      }
      #pragma unroll
      for (int ni = 0; ni < 8; ++ni) {
        const int row = wn * 128 + ni * 16 + cl;
        bv[ni] = *(const bf16x8*)(Bs + row * 128 + (kk2 ^ ((row & 7) << 4)));
      }
      #pragma unroll
      for (int mi = 0; mi < 4; ++mi)
        #pragma unroll
        for (int ni = 0; ni < 8; ++ni)
          acc[mi][ni] = __builtin_amdgcn_mfma_f32_16x16x32_bf16(
              av[mi], bv[ni], acc[mi][ni], 0, 0, 0);
    }
    __syncthreads();               // reads of cur done + prefetch landed
    cur ^= 1;
  }
  #undef LDA
  #undef WRA
  #undef STAGE_B

  // ---- epilogue ----
  unsigned short* hs = (unsigned short*)smem;        // [64][264] per chunk
  float* redS  = (float*)(smem + 36864);             // [256][2]
  float* redS2 = (float*)(smem + 38912);
  float* redP  = (float*)(smem + 40960);
  float* redC  = (float*)(smem + 43008);

  float bfn[8], gvn[8], bvn[8], a1n[8], a2n[8];
  #pragma unroll
  for (int ni = 0; ni < 8; ++ni) {
    const int c = wn * 128 + ni * 16 + cl;
    bfn[ni] = bfc[n * HID + c];
    gvn[ni] = lng[n * HID + c];
    bvn[ni] = lnb[n * HID + c];
    a1n[ni] = aw[n * (2 * HID) + c];
    a2n[ni] = aw[n * (2 * HID) + HID + c];
  }

  // E1: per-row sum / sumsq (this wave covers half the row -> LDS combine)
  #pragma unroll
  for (int mi = 0; mi < 4; ++mi) {
    #pragma unroll
    for (int r = 0; r < 4; ++r) {
      float s = 0.f, s2 = 0.f;
      #pragma unroll
      for (int ni = 0; ni < 8; ++ni) {
        const float x = acc[mi][ni][r] + bfn[ni];
        acc[mi][ni][r] = x;
        s += x; s2 += x * x;
      }
      s = red16(s); s2 = red16(s2);
      if (cl == 0) {
        const int row = wm * 64 + mi * 16 + rg * 4 + r;
        redS [row * 2 + wn] = s;
        redS2[row * 2 + wn] = s2;
      }
    }
  }
  __syncthreads();

  // E2: normalize, a1/a2 dots
  #pragma unroll
  for (int mi = 0; mi < 4; ++mi) {
    #pragma unroll
    for (int r = 0; r < 4; ++r) {
      const int row = wm * 64 + mi * 16 + rg * 4 + r;
      const float st  = redS [row * 2] + redS [row * 2 + 1];
      const float s2t = redS2[row * 2] + redS2[row * 2 + 1];
      const float mu  = st * (1.f / HID);
      const float var = s2t * (1.f / HID) - mu * mu;
      const float rs  = rsqrtf(var + 1e-5f);
      float pr = 0.f, pc = 0.f;
      #pragma unroll
      for (int ni = 0; ni < 8; ++ni) {
        const float hv = (acc[mi][ni][r] - mu) * rs * gvn[ni] + bvn[ni];
        acc[mi][ni][r] = hv;
        pr += hv * a1n[ni]; pc += hv * a2n[ni];
      }
      pr = red16(pr); pc = red16(pc);
      if (cl == 0) { redP[row * 2 + wn] = pr; redC[row * 2 + wn] = pc; }
    }
  }
  __syncthreads();
  if (t < 256) {
    // pre-scale by log2(e): downstream softmax runs in log2 domain
    sR[n * RTOT + row0 + t] = (redP[t * 2] + redP[t * 2 + 1]) * L2E;
    sC[n * RTOT + row0 + t] = (redC[t * 2] + redC[t * 2 + 1]) * L2E;
  }

  // E3: h store via LDS bounce, 4 chunks (chunk c = fragment-row group mi=c)
  unsigned short* hgb = hb + ((size_t)n * RTOT + row0) * HID;
  #pragma unroll
  for (int c = 0; c < 4; ++c) {
    #pragma unroll
    for (int ni = 0; ni < 8; ++ni)
      #pragma unroll
      for (int r = 0; r < 4; ++r) {
        const int lr  = wm * 16 + rg * 4 + r;
        const int col = wn * 128 + ni * 16 + cl;
        hs[lr * 264 + col] = f2b(acc[c][ni][r]);
      }
    __syncthreads();
    #pragma unroll
    for (int i = 0; i < 4; ++i) {
      const int idx = i * 4096 + t * 8;
      const int lr = idx >> 8, cc = idx & 255;
      const int grow = (lr >> 4) * 64 + c * 16 + (lr & 15);
      *(bf16x8*)&hgb[(size_t)grow * HID + cc] = *(const bf16x8*)&hs[lr * 264 + cc];
    }
    __syncthreads();
  }
}

// K2a (log2 domain): q'[i] = m' + log2(sum_j 2^(lrelu(c'_i + r'_j) - m'))
__global__ __launch_bounds__(256) void k2_lse(
    const float* __restrict__ sR, const float* __restrict__ sC,
    const float* __restrict__ ab, float* __restrict__ q)
{
  const int n  = blockIdx.x >> 7;
  const int b  = (blockIdx.x >> 3) & 15;
  const int ic = blockIdx.x & 7;
  const int t  = threadIdx.x;
  const int base = (n * BB + b) * LL;

  __shared__ float rl[LL];
  __shared__ float r01l[LL];
  __shared__ float red[4];

  const float4 r4 = ((const float4*)(sR + base))[t];
  ((float4*)rl)[t] = r4;
  float4 r01;
  r01.x = 0.01f * r4.x; r01.y = 0.01f * r4.y;
  r01.z = 0.01f * r4.z; r01.w = 0.01f * r4.w;
  ((float4*)r01l)[t] = r01;
  float tm = fmaxf(fmaxf(r4.x, r4.y), fmaxf(r4.z, r4.w));
  tm = waveReduceMax(tm);
  if ((t & 63) == 0) red[t >> 6] = tm;
  __syncthreads();
  const float rmax = fmaxf(fmaxf(red[0], red[1]), fmaxf(red[2], red[3]));

  const int i  = ic * 128 + (t >> 1);
  const int jh = t & 1;
  const float ci = sC[base + i] + ab[n] * L2E;
  const float m  = lrelu(ci + rmax);
  const float a1 = ci - m;
  const float a2 = 0.01f * ci - m;
  float z0 = 0.f, z1 = 0.f, z2 = 0.f, z3 = 0.f;
  #pragma unroll 4
  for (int j4 = jh * 128; j4 < jh * 128 + 128; ++j4) {
    const float4 rr = ((const float4*)rl)[j4];
    const float4 r0 = ((const float4*)r01l)[j4];
    z0 += EXP2(fmaxf(a1 + rr.x, a2 + r0.x));
    z1 += EXP2(fmaxf(a1 + rr.y, a2 + r0.y));
    z2 += EXP2(fmaxf(a1 + rr.z, a2 + r0.z));
    z3 += EXP2(fmaxf(a1 + rr.w, a2 + r0.w));
  }
  float z = (z0 + z1) + (z2 + z3);
  z += __shfl_xor(z, 1, 64);
  if (!jh) q[base + i] = m + LOG2(z);
}

// K23 (log2 domain): fused colsum + weighted h-sum.
__global__ __launch_bounds__(256) void k23_colw(
    const unsigned short* __restrict__ h, const float* __restrict__ sR,
    const float* __restrict__ sC, const float* __restrict__ ab,
    const float* __restrict__ q, float* __restrict__ partial)
{
  const int n  = blockIdx.x >> 7;
  const int b  = (blockIdx.x >> 3) & 15;
  const int jc = blockIdx.x & 7;
  const int t  = threadIdx.x;
  const int base = (n * BB + b) * LL;

  __shared__ float cls1[LL];
  __shared__ float cls2[LL];
  __shared__ float wl[128];
  __shared__ float red2[8][256];

  {
    const float4 c4 = ((const float4*)(sC + base))[t];
    const float4 q4 = ((const float4*)(q + base))[t];
    float4 v1, v2;
    v1.x = c4.x - q4.x; v2.x = 0.01f * c4.x - q4.x;
    v1.y = c4.y - q4.y; v2.y = 0.01f * c4.y - q4.y;
    v1.z = c4.z - q4.z; v2.z = 0.01f * c4.z - q4.z;
    v1.w = c4.w - q4.w; v2.w = 0.01f * c4.w - q4.w;
    ((float4*)cls1)[t] = v1;
    ((float4*)cls2)[t] = v2;
  }
  __syncthreads();

  {
    const int j  = jc * 128 + (t >> 1);
    const int ih = t & 1;
    const float rj  = sR[base + j] + ab[n] * L2E;
    const float r01 = 0.01f * rj;
    float z0 = 0.f, z1 = 0.f, z2 = 0.f, z3 = 0.f;
    #pragma unroll 4
    for (int i4 = ih * 128; i4 < ih * 128 + 128; ++i4) {
      const float4 c1 = ((const float4*)cls1)[i4];
      const float4 c2 = ((const float4*)cls2)[i4];
      z0 += EXP2(fmaxf(c1.x + rj, c2.x + r01));
      z1 += EXP2(fmaxf(c1.y + rj, c2.y + r01));
      z2 += EXP2(fmaxf(c1.z + rj, c2.z + r01));
      z3 += EXP2(fmaxf(c1.w + rj, c2.w + r01));
    }
    float z = (z0 + z1) + (z2 + z3);
    z += __shfl_xor(z, 1, 64);
    if (!ih) wl[t >> 1] = z * (1.f / LL);
  }
  __syncthreads();

  const int jl = t >> 5;
  const int cg = t & 31;
  const unsigned short* hp =
      h + ((size_t)n * RTOT + b * LL + jc * 128) * HID + cg * 8;
  float a0=0,a1=0,a2=0,a3=0,a4=0,a5=0,a6=0,a7=0;
  #pragma unroll 4
  for (int j = jl; j < 128; j += 8) {
    const bf16x8 v = *(const bf16x8*)(hp + (size_t)j * HID);
    const float w = wl[j];
    a0 = fmaf(w, b2f((unsigned short)v[0]), a0);
    a1 = fmaf(w, b2f((unsigned short)v[1]), a1);
    a2 = fmaf(w, b2f((unsigned short)v[2]), a2);
    a3 = fmaf(w, b2f((unsigned short)v[3]), a3);
    a4 = fmaf(w, b2f((unsigned short)v[4]), a4);
    a5 = fmaf(w, b2f((unsigned short)v[5]), a5);
    a6 = fmaf(w, b2f((unsigned short)v[6]), a6);
    a7 = fmaf(w, b2f((unsigned short)v[7]), a7);
  }
  red2[jl][cg*8+0]=a0; red2[jl][cg*8+1]=a1; red2[jl][cg*8+2]=a2; red2[jl][cg*8+3]=a3;
  red2[jl][cg*8+4]=a4; red2[jl][cg*8+5]=a5; red2[jl][cg*8+6]=a6; red2[jl][cg*8+7]=a7;
  __syncthreads();
  float s = 0.f;
  #pragma unroll
  for (int r = 0; r < 8; ++r) s += red2[r][t];
  partial[((n * BB + b) * 8 + jc) * 256 + t] = s;
}

// K4a: K-split partial GEMM (sent_raw reduce folded into staging)
__global__ __launch_bounds__(256) void k4_cat(
    const float* __restrict__ partial, const float* __restrict__ Wcat,
    float* __restrict__ pcat)
{
  const int kc = blockIdx.x / 3;
  const int oc = blockIdx.x % 3;
  const int t  = threadIdx.x;
  __shared__ float s[64][16];
  {
    const int kk = t >> 2, b4 = (t & 3) * 4;
    const int n = kc >> 2;
    const int c = (kc & 3) * 64 + kk;
    #pragma unroll
    for (int bi = 0; bi < 4; ++bi) {
      const int b = b4 + bi;
      const float* pb = partial + (size_t)((n * BB + b) * 8) * 256 + c;
      float v = 0.f;
      #pragma unroll
      for (int j = 0; j < 8; ++j) v += pb[j * 256];
      s[kk][b] = v;
    }
  }
  __syncthreads();
  const int o = oc * 256 + t;
  const float* W = Wcat + (size_t)(kc * 64) * OD + o;
  float acc[BB];
  #pragma unroll
  for (int b = 0; b < BB; ++b) acc[b] = 0.f;
  #pragma unroll 4
  for (int kk = 0; kk < 64; ++kk) {
    const float w = W[(size_t)kk * OD];
    const f32x4 s0 = *(const f32x4*)&s[kk][0];
    const f32x4 s1 = *(const f32x4*)&s[kk][4];
    const f32x4 s2 = *(const f32x4*)&s[kk][8];
    const f32x4 s3 = *(const f32x4*)&s[kk][12];
    acc[0]=fmaf(s0.x,w,acc[0]);  acc[1]=fmaf(s0.y,w,acc[1]);
    acc[2]=fmaf(s0.z,w,acc[2]);  acc[3]=fmaf(s0.w,w,acc[3]);
    acc[4]=fmaf(s1.x,w,acc[4]);  acc[5]=fmaf(s1.y,w,acc[5]);
    acc[6]=fmaf(s1.z,w,acc[6]);  acc[7]=fmaf(s1.w,w,acc[7]);
    acc[8]=fmaf(s2.x,w,acc[8]);  acc[9]=fmaf(s2.y,w,acc[9]);
    acc[10]=fmaf(s2.z,w,acc[10]); acc[11]=fmaf(s2.w,w,acc[11]);
    acc[12]=fmaf(s3.x,w,acc[12]); acc[13]=fmaf(s3.y,w,acc[13]);
    acc[14]=fmaf(s3.z,w,acc[14]); acc[15]=fmaf(s3.w,w,acc[15]);
  }
  float* P = pcat + (size_t)(kc * BB) * OD + o;
  #pragma unroll
  for (int b = 0; b < BB; ++b) P[(size_t)b * OD] = acc[b];
}

// K4b: sent = LN(bcat + sum_kc pcat)
__global__ __launch_bounds__(256) void k4_ln(
    const float* __restrict__ pcat, const float* __restrict__ bcat,
    const float* __restrict__ g, const float* __restrict__ be,
    float* __restrict__ sent, float* __restrict__ out_sent)
{
  const int b = blockIdx.x;
  const int t = threadIdx.x;
  __shared__ float red[4][2];
  float x[3];
  #pragma unroll
  for (int i = 0; i < 3; ++i) {
    const int o = i * 256 + t;
    float v = bcat[o];
    #pragma unroll
    for (int kc = 0; kc < 16; ++kc) v += pcat[(size_t)(kc * BB + b) * OD + o];
    x[i] = v;
  }
  float s  = x[0] + x[1] + x[2];
  float s2 = x[0]*x[0] + x[1]*x[1] + x[2]*x[2];
  s = waveReduceSum(s); s2 = waveReduceSum(s2);
  if ((t & 63) == 0) { red[t >> 6][0] = s; red[t >> 6][1] = s2; }
  __syncthreads();
  s  = red[0][0] + red[1][0] + red[2][0] + red[3][0];
  s2 = red[0][1] + red[1][1] + red[2][1] + red[3][1];
  const float mu  = s * (1.f / OD);
  const float var = s2 * (1.f / OD) - mu * mu;
  const float rs  = rsqrtf(var + 1e-5f);
  #pragma unroll
  for (int i = 0; i < 3; ++i) {
    const int o = i * 256 + t;
    const float y = (x[i] - mu) * rs * g[o] + be[o];
    sent[b * OD + o]     = y;
    out_sent[b * OD + o] = y;
  }
}

// K4c: K-split partials for the three output FCs.
__global__ __launch_bounds__(256) void k4_fcs(
    const float* __restrict__ sent, const float* __restrict__ Wfcs,
    float* __restrict__ pfcs)
{
  const int kc = blockIdx.x / 9;
  const int r  = blockIdx.x % 9;
  const int i  = r / 3, oc = r % 3;
  const int t  = threadIdx.x;
  __shared__ float s[64][16];
  {
    const int kk = t >> 2, b4 = (t & 3) * 4;
    #pragma unroll
    for (int bi = 0; bi < 4; ++bi)
      s[kk][b4 + bi] = sent[(b4 + bi) * OD + kc * 64 + kk];
  }
  __syncthreads();
  const int o = oc * 256 + t;
  const float* W = Wfcs + (size_t)i * OD * OD + (size_t)(kc * 64) * OD + o;
  float acc[BB];
  #pragma unroll
  for (int b = 0; b < BB; ++b) acc[b] = 0.f;
  #pragma unroll 4
  for (int kk = 0; kk < 64; ++kk) {
    const float w = W[(size_t)kk * OD];
    const f32x4 s0 = *(const f32x4*)&s[kk][0];
    const f32x4 s1 = *(const f32x4*)&s[kk][4];
    const f32x4 s2 = *(const f32x4*)&s[kk][8];
    const f32x4 s3 = *(const f32x4*)&s[kk][12];
    acc[0]=fmaf(s0.x,w,acc[0]);  acc[1]=fmaf(s0.y,w,acc[1]);
    acc[2]=fmaf(s0.z,w,acc[2]);  acc[3]=fmaf(s0.w,w,acc[3]);
    acc[4]=fmaf(s1.x,w,acc[4]);  acc[5]=fmaf(s1.y,w,acc[5]);
    acc[6]=fmaf(s1.z,w,acc[6]);  acc[7]=fmaf(s1.w,w,acc[7]);
    acc[8]=fmaf(s2.x,w,acc[8]);  acc[9]=fmaf(s2.y,w,acc[9]);
    acc[10]=fmaf(s2.z,w,acc[10]); acc[11]=fmaf(s2.w,w,acc[11]);
    acc[12]=fmaf(s3.x,w,acc[12]); acc[13]=fmaf(s3.y,w,acc[13]);
    acc[14]=fmaf(s3.z,w,acc[14]); acc[15]=fmaf(s3.w,w,acc[15]);
  }
  float* P = pfcs + (size_t)((kc * 3 + i) * BB) * OD + o;
  #pragma unroll
  for (int b = 0; b < BB; ++b) P[(size_t)b * OD] = acc[b];
}

// K4d: out[i][b][o] = bfcs[i,o] + sum_kc pfcs
__global__ __launch_bounds__(256) void k4_red(
    const float* __restrict__ pfcs, const float* __restrict__ bfcs,
    float* __restrict__ out)
{
  const int i = blockIdx.x >> 4;
  const int b = blockIdx.x & 15;
  const int t = threadIdx.x;
  #pragma unroll
  for (int oc = 0; oc < 3; ++oc) {
    const int o = oc * 256 + t;
    float v = bfcs[i * OD + o];
    #pragma unroll
    for (int kc = 0; kc < 12; ++kc)
      v += pfcs[(size_t)((kc * 3 + i) * BB + b) * OD + o];
    out[i * (BB * OD) + b * OD + o] = v;
  }
}

extern "C" void kernel_launch(void* const* d_in, const int* in_sizes, int n_in,
                              void* d_out, int out_size, void* d_ws, size_t ws_size,
                              hipStream_t stream)
{
  const float* T    = (const float*)d_in[0];
  const float* Wfc  = (const float*)d_in[1];
  const float* bfc  = (const float*)d_in[2];
  const float* lng  = (const float*)d_in[3];
  const float* lnb  = (const float*)d_in[4];
  const float* aw   = (const float*)d_in[5];
  const float* ab   = (const float*)d_in[6];
  const float* Wcat = (const float*)d_in[7];
  const float* bcat = (const float*)d_in[8];
  const float* lnOg = (const float*)d_in[9];
  const float* lnOb = (const float*)d_in[10];
  const float* Wfcs = (const float*)d_in[11];
  const float* bfcs = (const float*)d_in[12];
  float* out = (float*)d_out;

  char* W = (char*)d_ws;
  unsigned short* Wtb = (unsigned short*)W;                 //  1,572,864 B
  unsigned short* hb  = (unsigned short*)(W + 1572864);     // 33,554,432 B
  float* sR      = (float*)(W + 35127296);
  float* sC      = sR + NH * RTOT;
  float* q       = sC + NH * RTOT;
  float* partial = q + NH * RTOT;                           // 131072 f
  float* sent    = partial + NH * BB * 8 * 256;
  float* pcat    = sent + BB * OD;
  float* pfcs    = pcat + 16 * BB * OD;

  kconv_w <<<dim3(192),  dim3(256), 0, stream>>>(Wfc, Wtb);
  k1_mfma <<<dim3(256),  dim3(512), 0, stream>>>(T, Wtb, bfc, lng, lnb, aw, hb, sR, sC);
  k2_lse  <<<dim3(512),  dim3(256), 0, stream>>>(sR, sC, ab, q);
  k23_colw<<<dim3(512),  dim3(256), 0, stream>>>(hb, sR, sC, ab, q, partial);
  k4_cat  <<<dim3(48),   dim3(256), 0, stream>>>(partial, Wcat, pcat);
  k4_ln   <<<dim3(16),   dim3(256), 0, stream>>>(pcat, bcat, lnOg, lnOb, sent, out + 3 * BB * OD);
  k4_fcs  <<<dim3(108),  dim3(256), 0, stream>>>(sent, Wfcs, pfcs);
  k4_red  <<<dim3(48),   dim3(256), 0, stream>>>(pfcs, bfcs, out);
}